// Round 1
// baseline (1146.056 us; speedup 1.0000x reference)
//
#include <hip/hip_runtime.h>
#include <hip/hip_bf16.h>

#define NNODES 50000
#define NEDGES 800000
#define NFEAT  512
#define NHID   64
#define NCLASS 40

// ---------------------------------------------------------------------------
// GEMM1: out[r,c] = b[c] + sum_k x[r,k] * W[k,c]   (x: 50000x512, W: 512x64)
// block = 256 threads = 4 waves; each wave handles one row, lane = column.
// x reads are wave-broadcast (same address), W reads are coalesced (64 floats).
// ---------------------------------------------------------------------------
__global__ __launch_bounds__(256) void gemm1_kernel(
    const float* __restrict__ x, const float* __restrict__ W,
    const float* __restrict__ b, float* __restrict__ out) {
    const int c = threadIdx.x & 63;
    const int r = blockIdx.x * 4 + (threadIdx.x >> 6);
    if (r >= NNODES) return;
    const float* xr = x + (size_t)r * NFEAT;
    float acc = b[c];
    #pragma unroll 4
    for (int k = 0; k < NFEAT; k += 4) {
        const float4 xv = *(const float4*)(xr + k);
        acc += xv.x * W[(k + 0) * NHID + c];
        acc += xv.y * W[(k + 1) * NHID + c];
        acc += xv.z * W[(k + 2) * NHID + c];
        acc += xv.w * W[(k + 3) * NHID + c];
    }
    out[(size_t)r * NHID + c] = acc;
}

// ---------------------------------------------------------------------------
// GEMM2: out[r,c] = b[c] + sum_k relu(h[r,k]) * W[k,c]   (h: 50000x64, W: 64x64)
// ReLU fused into the read of h (layer-1 activation).
// ---------------------------------------------------------------------------
__global__ __launch_bounds__(256) void gemm2_relu_kernel(
    const float* __restrict__ h, const float* __restrict__ W,
    const float* __restrict__ b, float* __restrict__ out) {
    const int c = threadIdx.x & 63;
    const int r = blockIdx.x * 4 + (threadIdx.x >> 6);
    if (r >= NNODES) return;
    const float* hr = h + (size_t)r * NHID;
    float acc = b[c];
    #pragma unroll 4
    for (int k = 0; k < NHID; k += 4) {
        const float4 hv = *(const float4*)(hr + k);
        acc += fmaxf(hv.x, 0.f) * W[(k + 0) * NHID + c];
        acc += fmaxf(hv.y, 0.f) * W[(k + 1) * NHID + c];
        acc += fmaxf(hv.z, 0.f) * W[(k + 2) * NHID + c];
        acc += fmaxf(hv.w, 0.f) * W[(k + 3) * NHID + c];
    }
    out[(size_t)r * NHID + c] = acc;
}

// ---------------------------------------------------------------------------
// GEMM3: out[r,c] = b[c] + sum_k h[r,k] * W[k,c]   (h: 50000x64, W: 64x40)
// wave per row; lanes 40..63 idle (avoids integer div; keeps broadcast loads).
// ---------------------------------------------------------------------------
__global__ __launch_bounds__(256) void gemm3_kernel(
    const float* __restrict__ h, const float* __restrict__ W,
    const float* __restrict__ b, float* __restrict__ out) {
    const int c = threadIdx.x & 63;
    const int r = blockIdx.x * 4 + (threadIdx.x >> 6);
    if (r >= NNODES || c >= NCLASS) return;
    const float* hr = h + (size_t)r * NHID;
    float acc = b[c];
    #pragma unroll 4
    for (int k = 0; k < NHID; k += 4) {
        const float4 hv = *(const float4*)(hr + k);
        acc += hv.x * W[(k + 0) * NCLASS + c];
        acc += hv.y * W[(k + 1) * NCLASS + c];
        acc += hv.z * W[(k + 2) * NCLASS + c];
        acc += hv.w * W[(k + 3) * NCLASS + c];
    }
    out[(size_t)r * NCLASS + c] = acc;
}

// ---------------------------------------------------------------------------
// SpMM (64 feats): out[row[e], f] += sup[col[e], f] * ew[e]
// wave per edge, lane = feature. Gather coalesced, atomics to 64 consecutive
// floats. row/col/ew loads are wave-uniform (broadcast).
// ---------------------------------------------------------------------------
__global__ __launch_bounds__(256) void spmm64_kernel(
    const float* __restrict__ sup, const float* __restrict__ ew,
    const int* __restrict__ row, const int* __restrict__ col,
    float* __restrict__ out) {
    const int f = threadIdx.x & 63;
    const int e = blockIdx.x * 4 + (threadIdx.x >> 6);
    if (e >= NEDGES) return;
    const float v = sup[(size_t)col[e] * NHID + f] * ew[e];
    atomicAdd(&out[(size_t)row[e] * NHID + f], v);
}

// ---------------------------------------------------------------------------
// SpMM (40 feats): same, lanes 40..63 idle.
// ---------------------------------------------------------------------------
__global__ __launch_bounds__(256) void spmm40_kernel(
    const float* __restrict__ sup, const float* __restrict__ ew,
    const int* __restrict__ row, const int* __restrict__ col,
    float* __restrict__ out) {
    const int f = threadIdx.x & 63;
    const int e = blockIdx.x * 4 + (threadIdx.x >> 6);
    if (e >= NEDGES || f >= NCLASS) return;
    const float v = sup[(size_t)col[e] * NCLASS + f] * ew[e];
    atomicAdd(&out[(size_t)row[e] * NCLASS + f], v);
}

// ---------------------------------------------------------------------------
// log_softmax over rows of 40: out = x - (max + log(sum(exp(x - max))))
// one thread per row (small tensor, L2-resident).
// ---------------------------------------------------------------------------
__global__ __launch_bounds__(256) void logsoftmax_kernel(
    const float* __restrict__ in, float* __restrict__ out) {
    const int r = blockIdx.x * 256 + threadIdx.x;
    if (r >= NNODES) return;
    const float* xr = in + (size_t)r * NCLASS;
    float m = -1e30f;
    #pragma unroll
    for (int i = 0; i < NCLASS; ++i) m = fmaxf(m, xr[i]);
    float s = 0.f;
    #pragma unroll
    for (int i = 0; i < NCLASS; ++i) s += __expf(xr[i] - m);
    const float ls = __logf(s) + m;
    float* orow = out + (size_t)r * NCLASS;
    #pragma unroll
    for (int i = 0; i < NCLASS; ++i) orow[i] = xr[i] - ls;
}

extern "C" void kernel_launch(void* const* d_in, const int* in_sizes, int n_in,
                              void* d_out, int out_size, void* d_ws, size_t ws_size,
                              hipStream_t stream) {
    const float* x  = (const float*)d_in[0];
    const float* ew = (const float*)d_in[1];
    const float* W1 = (const float*)d_in[2];
    const float* b1 = (const float*)d_in[3];
    const float* W2 = (const float*)d_in[4];
    const float* b2 = (const float*)d_in[5];
    const float* W3 = (const float*)d_in[6];
    const float* b3 = (const float*)d_in[7];
    const int* row  = (const int*)d_in[8];
    const int* col  = (const int*)d_in[9];
    float* out = (float*)d_out;

    // Workspace layout (ws re-poisoned to 0xAA before every call — we memset
    // what needs zeroing):
    //   A: 50000*64 floats (12.8 MB)  -- support1, then support2, then h3
    //   B: 50000*64 floats (12.8 MB)  -- h1 (pre-relu), then h2
    //   C: 50000*40 floats (8.0 MB)   -- support3
    const size_t n64 = (size_t)NNODES * NHID;
    const size_t n40 = (size_t)NNODES * NCLASS;
    float* A = (float*)d_ws;
    float* B = A + n64;
    float* C = B + n64;

    const int gemmBlocks = (NNODES + 3) / 4;   // 4 rows / block
    const int spmmBlocks = (NEDGES + 3) / 4;   // 4 edges / block

    // Layer 1: support1 = x@W1 + b1 ; h1 = segsum(support1[col]*ew)
    gemm1_kernel<<<gemmBlocks, 256, 0, stream>>>(x, W1, b1, A);
    hipMemsetAsync(B, 0, n64 * sizeof(float), stream);
    spmm64_kernel<<<spmmBlocks, 256, 0, stream>>>(A, ew, row, col, B);

    // Layer 2: support2 = relu(h1)@W2 + b2 ; h2 = segsum(...)
    gemm2_relu_kernel<<<gemmBlocks, 256, 0, stream>>>(B, W2, b2, A);
    hipMemsetAsync(B, 0, n64 * sizeof(float), stream);   // after gemm2 read B
    spmm64_kernel<<<spmmBlocks, 256, 0, stream>>>(A, ew, row, col, B);

    // Layer 3: support3 = h2@W3 + b3 ; h3 = segsum(...)
    gemm3_kernel<<<gemmBlocks, 256, 0, stream>>>(B, W3, b3, C);
    hipMemsetAsync(A, 0, n40 * sizeof(float), stream);   // A reused as h3
    spmm40_kernel<<<spmmBlocks, 256, 0, stream>>>(C, ew, row, col, A);

    // log_softmax -> d_out
    logsoftmax_kernel<<<(NNODES + 255) / 256, 256, 0, stream>>>(A, out);
}

// Round 2
// 809.657 us; speedup vs baseline: 1.4155x; 1.4155x over previous
//
#include <hip/hip_runtime.h>
#include <hip/hip_bf16.h>

#define NNODES 50000
#define NEDGES 800000
#define NFEAT  512
#define NHID   64
#define NCLASS 40

// ---------------------------------------------------------------------------
// Tiled fp32 GEMM: out[r,c] = b[c] + sum_k act(x[r,k]) * W[k,c]
//   x: [NNODES, K], W: [K, 64], out: [NNODES, 64]
// Block = 256 threads, tile = 64 rows x 64 cols, BK = 32.
// x tile staged TRANSPOSED in LDS (stride 68 keeps float4 reads 16B-aligned);
// inner-loop x reads are wave-broadcast (free), W reads are 2-way (free).
// Each thread: c = tid&63, 16 rows -> 16 FMAs per W-scalar read.
// ---------------------------------------------------------------------------
template<int K, bool RELU>
__global__ __launch_bounds__(256) void tiled_gemm_kernel(
    const float* __restrict__ x, const float* __restrict__ W,
    const float* __restrict__ b, float* __restrict__ out) {
    __shared__ float xs[32 * 68];   // [kk][row], stride 68
    __shared__ float Ws[32 * 64];   // [kk][col]

    const int tid = threadIdx.x;
    const int c  = tid & 63;
    const int rg = tid >> 6;              // 0..3, 16 rows each
    const int r0 = blockIdx.x * 64;

    float acc[16];
    #pragma unroll
    for (int i = 0; i < 16; ++i) acc[i] = 0.f;

    // staging index precompute
    const int xrow  = tid >> 3;           // 0..31 (two passes: +0, +32)
    const int xcol4 = (tid & 7) * 4;      // 0,4,..,28
    const int wrow  = tid >> 4;           // 0..15 (two passes: +0, +16)
    const int wcol4 = (tid & 15) * 4;     // 0,4,..,60

    for (int kb = 0; kb < K; kb += 32) {
        // ---- stage x tile (64 rows x 32 cols), transposed ----
        #pragma unroll
        for (int i = 0; i < 2; ++i) {
            const int row = xrow + i * 32;
            const int gr  = r0 + row;
            float4 v = make_float4(0.f, 0.f, 0.f, 0.f);
            if (gr < NNODES)
                v = *(const float4*)(x + (size_t)gr * K + kb + xcol4);
            if (RELU) {
                v.x = fmaxf(v.x, 0.f); v.y = fmaxf(v.y, 0.f);
                v.z = fmaxf(v.z, 0.f); v.w = fmaxf(v.w, 0.f);
            }
            xs[(xcol4 + 0) * 68 + row] = v.x;
            xs[(xcol4 + 1) * 68 + row] = v.y;
            xs[(xcol4 + 2) * 68 + row] = v.z;
            xs[(xcol4 + 3) * 68 + row] = v.w;
        }
        // ---- stage W tile (32 rows x 64 cols) ----
        #pragma unroll
        for (int i = 0; i < 2; ++i) {
            const int wr = wrow + i * 16;
            *(float4*)&Ws[wr * 64 + wcol4] =
                *(const float4*)(W + (size_t)(kb + wr) * 64 + wcol4);
        }
        __syncthreads();

        // ---- inner product ----
        #pragma unroll 4
        for (int kk = 0; kk < 32; ++kk) {
            const float w = Ws[kk * 64 + c];
            const float4* xt = (const float4*)&xs[kk * 68 + rg * 16];
            const float4 a0 = xt[0], a1 = xt[1], a2 = xt[2], a3 = xt[3];
            acc[0]  += a0.x * w; acc[1]  += a0.y * w;
            acc[2]  += a0.z * w; acc[3]  += a0.w * w;
            acc[4]  += a1.x * w; acc[5]  += a1.y * w;
            acc[6]  += a1.z * w; acc[7]  += a1.w * w;
            acc[8]  += a2.x * w; acc[9]  += a2.y * w;
            acc[10] += a2.z * w; acc[11] += a2.w * w;
            acc[12] += a3.x * w; acc[13] += a3.y * w;
            acc[14] += a3.z * w; acc[15] += a3.w * w;
        }
        __syncthreads();
    }

    const float bias = b[c];
    #pragma unroll
    for (int i = 0; i < 16; ++i) {
        const int gr = r0 + rg * 16 + i;
        if (gr < NNODES) out[(size_t)gr * 64 + c] = acc[i] + bias;
    }
}

// ---------------------------------------------------------------------------
// GEMM3: out[r,c] = b[c] + sum_k h[r,k] * W[k,c]   (h: 50000x64, W: 64x40)
// wave per row; lanes 40..63 idle. W3 (10KB) fits L1 -> cheap.
// ---------------------------------------------------------------------------
__global__ __launch_bounds__(256) void gemm3_kernel(
    const float* __restrict__ h, const float* __restrict__ W,
    const float* __restrict__ b, float* __restrict__ out) {
    const int c = threadIdx.x & 63;
    const int r = blockIdx.x * 4 + (threadIdx.x >> 6);
    if (r >= NNODES || c >= NCLASS) return;
    const float* hr = h + (size_t)r * NHID;
    float acc = b[c];
    #pragma unroll 4
    for (int k = 0; k < NHID; k += 4) {
        const float4 hv = *(const float4*)(hr + k);
        acc += hv.x * W[(k + 0) * NCLASS + c];
        acc += hv.y * W[(k + 1) * NCLASS + c];
        acc += hv.z * W[(k + 2) * NCLASS + c];
        acc += hv.w * W[(k + 3) * NCLASS + c];
    }
    out[(size_t)r * NCLASS + c] = acc;
}

// ---------------------------------------------------------------------------
// SpMM (64 feats): out[row[e], f] += sup[col[e], f] * ew[e]
// wave per edge, lane = feature. Gather coalesced, atomics coalesced.
// ---------------------------------------------------------------------------
__global__ __launch_bounds__(256) void spmm64_kernel(
    const float* __restrict__ sup, const float* __restrict__ ew,
    const int* __restrict__ row, const int* __restrict__ col,
    float* __restrict__ out) {
    const int f = threadIdx.x & 63;
    const int e = blockIdx.x * 4 + (threadIdx.x >> 6);
    if (e >= NEDGES) return;
    const float v = sup[(size_t)col[e] * NHID + f] * ew[e];
    atomicAdd(&out[(size_t)row[e] * NHID + f], v);
}

// ---------------------------------------------------------------------------
// SpMM (40 feats): same, lanes 40..63 idle.
// ---------------------------------------------------------------------------
__global__ __launch_bounds__(256) void spmm40_kernel(
    const float* __restrict__ sup, const float* __restrict__ ew,
    const int* __restrict__ row, const int* __restrict__ col,
    float* __restrict__ out) {
    const int f = threadIdx.x & 63;
    const int e = blockIdx.x * 4 + (threadIdx.x >> 6);
    if (e >= NEDGES || f >= NCLASS) return;
    const float v = sup[(size_t)col[e] * NCLASS + f] * ew[e];
    atomicAdd(&out[(size_t)row[e] * NCLASS + f], v);
}

// ---------------------------------------------------------------------------
// log_softmax over rows of 40.
// ---------------------------------------------------------------------------
__global__ __launch_bounds__(256) void logsoftmax_kernel(
    const float* __restrict__ in, float* __restrict__ out) {
    const int r = blockIdx.x * 256 + threadIdx.x;
    if (r >= NNODES) return;
    const float* xr = in + (size_t)r * NCLASS;
    float m = -1e30f;
    #pragma unroll
    for (int i = 0; i < NCLASS; ++i) m = fmaxf(m, xr[i]);
    float s = 0.f;
    #pragma unroll
    for (int i = 0; i < NCLASS; ++i) s += __expf(xr[i] - m);
    const float ls = __logf(s) + m;
    float* orow = out + (size_t)r * NCLASS;
    #pragma unroll
    for (int i = 0; i < NCLASS; ++i) orow[i] = xr[i] - ls;
}

extern "C" void kernel_launch(void* const* d_in, const int* in_sizes, int n_in,
                              void* d_out, int out_size, void* d_ws, size_t ws_size,
                              hipStream_t stream) {
    const float* x  = (const float*)d_in[0];
    const float* ew = (const float*)d_in[1];
    const float* W1 = (const float*)d_in[2];
    const float* b1 = (const float*)d_in[3];
    const float* W2 = (const float*)d_in[4];
    const float* b2 = (const float*)d_in[5];
    const float* W3 = (const float*)d_in[6];
    const float* b3 = (const float*)d_in[7];
    const int* row  = (const int*)d_in[8];
    const int* col  = (const int*)d_in[9];
    float* out = (float*)d_out;

    const size_t n64 = (size_t)NNODES * NHID;
    const size_t n40 = (size_t)NNODES * NCLASS;
    float* A = (float*)d_ws;        // support1 / support2 / h3
    float* B = A + n64;             // h1 / h2
    float* C = B + n64;             // support3

    const int tileBlocks = (NNODES + 63) / 64;
    const int rowBlocks  = (NNODES + 3) / 4;
    const int spmmBlocks = (NEDGES + 3) / 4;

    // Layer 1
    tiled_gemm_kernel<NFEAT, false><<<tileBlocks, 256, 0, stream>>>(x, W1, b1, A);
    hipMemsetAsync(B, 0, n64 * sizeof(float), stream);
    spmm64_kernel<<<spmmBlocks, 256, 0, stream>>>(A, ew, row, col, B);

    // Layer 2 (ReLU fused into staging read of h1)
    tiled_gemm_kernel<NHID, true><<<tileBlocks, 256, 0, stream>>>(B, W2, b2, A);
    hipMemsetAsync(B, 0, n64 * sizeof(float), stream);
    spmm64_kernel<<<spmmBlocks, 256, 0, stream>>>(A, ew, row, col, B);

    // Layer 3
    gemm3_kernel<<<rowBlocks, 256, 0, stream>>>(B, W3, b3, C);
    hipMemsetAsync(A, 0, n40 * sizeof(float), stream);
    spmm40_kernel<<<spmmBlocks, 256, 0, stream>>>(C, ew, row, col, A);

    logsoftmax_kernel<<<(NNODES + 255) / 256, 256, 0, stream>>>(A, out);
}

// Round 3
// 548.703 us; speedup vs baseline: 2.0887x; 1.4756x over previous
//
#include <hip/hip_runtime.h>
#include <hip/hip_bf16.h>

#define NNODES 50000
#define NEDGES 800000
#define NFEAT  512
#define NHID   64
#define NCLASS 40

#define SCAN_CHUNK 1024                      // elements per scan1 block
#define SCAN_BLOCKS ((NNODES + SCAN_CHUNK - 1) / SCAN_CHUNK)   // 49

// ===========================================================================
// CSR build (per call; inputs are restored every launch so we rebuild).
// ===========================================================================

// deg[r] = number of edges with row==r
__global__ __launch_bounds__(256) void hist_kernel(
    const int* __restrict__ row, int* __restrict__ deg) {
    const int e = blockIdx.x * 256 + threadIdx.x;
    if (e < NEDGES) atomicAdd(&deg[row[e]], 1);
}

// Per-block exclusive scan: 256 threads x 4 elements = 1024/block.
// Writes local-exclusive prefixes to row_start, block total to bsum.
__global__ __launch_bounds__(256) void scan1_kernel(
    const int* __restrict__ deg, int* __restrict__ row_start,
    int* __restrict__ bsum) {
    __shared__ int lds[256];
    const int t = threadIdx.x;
    const int base = blockIdx.x * SCAN_CHUNK + t * 4;
    int d0 = 0, d1 = 0, d2 = 0, d3 = 0;
    if (base + 0 < NNODES) d0 = deg[base + 0];
    if (base + 1 < NNODES) d1 = deg[base + 1];
    if (base + 2 < NNODES) d2 = deg[base + 2];
    if (base + 3 < NNODES) d3 = deg[base + 3];
    const int s = d0 + d1 + d2 + d3;
    lds[t] = s;
    __syncthreads();
    for (int o = 1; o < 256; o <<= 1) {
        int v = lds[t];
        if (t >= o) v += lds[t - o];
        __syncthreads();
        lds[t] = v;
        __syncthreads();
    }
    int p = lds[t] - s;                        // exclusive prefix of this thread
    if (base + 0 < NNODES) row_start[base + 0] = p;
    if (base + 1 < NNODES) row_start[base + 1] = p + d0;
    if (base + 2 < NNODES) row_start[base + 2] = p + d0 + d1;
    if (base + 3 < NNODES) row_start[base + 3] = p + d0 + d1 + d2;
    if (t == 255) bsum[blockIdx.x] = lds[255];
}

// Exclusive scan of the 49 block sums (single wave).
__global__ __launch_bounds__(64) void scan2_kernel(int* __restrict__ bsum) {
    const int t = threadIdx.x;
    const int orig = (t < SCAN_BLOCKS) ? bsum[t] : 0;
    int v = orig;
    for (int o = 1; o < 64; o <<= 1) {
        const int u = __shfl_up(v, o);
        if (t >= o) v += u;
    }
    bsum[t] = v - orig;                        // exclusive
}

// Add block offsets; duplicate into cursor for the scatter pass.
__global__ __launch_bounds__(256) void scan3_kernel(
    int* __restrict__ row_start, const int* __restrict__ bsum,
    int* __restrict__ cursor) {
    const int i = blockIdx.x * 256 + threadIdx.x;
    if (i < NNODES) {
        const int v = row_start[i] + bsum[i / SCAN_CHUNK];
        row_start[i] = v;
        cursor[i] = v;
    }
    if (i == 0) row_start[NNODES] = NEDGES;
}

// edges[pos] = (col, bitcast(ew)) in row-sorted order.
__global__ __launch_bounds__(256) void scatter_kernel(
    const int* __restrict__ row, const int* __restrict__ col,
    const float* __restrict__ ew, int* __restrict__ cursor,
    int2* __restrict__ edges) {
    const int e = blockIdx.x * 256 + threadIdx.x;
    if (e >= NEDGES) return;
    const int pos = atomicAdd(&cursor[row[e]], 1);
    edges[pos] = make_int2(col[e], __float_as_int(ew[e]));
}

// ===========================================================================
// Tiled fp32 GEMM: out[r,c] = b[c] + sum_k act(x[r,k]) * W[k,c]
// Block 256, tile 64x64, BK=32; x staged transposed (stride 68).
// ===========================================================================
template<int K, bool RELU>
__global__ __launch_bounds__(256) void tiled_gemm_kernel(
    const float* __restrict__ x, const float* __restrict__ W,
    const float* __restrict__ b, float* __restrict__ out) {
    __shared__ float xs[32 * 68];
    __shared__ float Ws[32 * 64];

    const int tid = threadIdx.x;
    const int c  = tid & 63;
    const int rg = tid >> 6;
    const int r0 = blockIdx.x * 64;

    float acc[16];
    #pragma unroll
    for (int i = 0; i < 16; ++i) acc[i] = 0.f;

    const int xrow  = tid >> 3;
    const int xcol4 = (tid & 7) * 4;
    const int wrow  = tid >> 4;
    const int wcol4 = (tid & 15) * 4;

    for (int kb = 0; kb < K; kb += 32) {
        #pragma unroll
        for (int i = 0; i < 2; ++i) {
            const int row = xrow + i * 32;
            const int gr  = r0 + row;
            float4 v = make_float4(0.f, 0.f, 0.f, 0.f);
            if (gr < NNODES)
                v = *(const float4*)(x + (size_t)gr * K + kb + xcol4);
            if (RELU) {
                v.x = fmaxf(v.x, 0.f); v.y = fmaxf(v.y, 0.f);
                v.z = fmaxf(v.z, 0.f); v.w = fmaxf(v.w, 0.f);
            }
            xs[(xcol4 + 0) * 68 + row] = v.x;
            xs[(xcol4 + 1) * 68 + row] = v.y;
            xs[(xcol4 + 2) * 68 + row] = v.z;
            xs[(xcol4 + 3) * 68 + row] = v.w;
        }
        #pragma unroll
        for (int i = 0; i < 2; ++i) {
            const int wr = wrow + i * 16;
            *(float4*)&Ws[wr * 64 + wcol4] =
                *(const float4*)(W + (size_t)(kb + wr) * 64 + wcol4);
        }
        __syncthreads();

        #pragma unroll 4
        for (int kk = 0; kk < 32; ++kk) {
            const float w = Ws[kk * 64 + c];
            const float4* xt = (const float4*)&xs[kk * 68 + rg * 16];
            const float4 a0 = xt[0], a1 = xt[1], a2 = xt[2], a3 = xt[3];
            acc[0]  += a0.x * w; acc[1]  += a0.y * w;
            acc[2]  += a0.z * w; acc[3]  += a0.w * w;
            acc[4]  += a1.x * w; acc[5]  += a1.y * w;
            acc[6]  += a1.z * w; acc[7]  += a1.w * w;
            acc[8]  += a2.x * w; acc[9]  += a2.y * w;
            acc[10] += a2.z * w; acc[11] += a2.w * w;
            acc[12] += a3.x * w; acc[13] += a3.y * w;
            acc[14] += a3.z * w; acc[15] += a3.w * w;
        }
        __syncthreads();
    }

    const float bias = b[c];
    #pragma unroll
    for (int i = 0; i < 16; ++i) {
        const int gr = r0 + rg * 16 + i;
        if (gr < NNODES) out[(size_t)gr * 64 + c] = acc[i] + bias;
    }
}

// ===========================================================================
// GEMM3: wave per row, lanes 40..63 idle (W3 is 10 KB, L1-resident).
// ===========================================================================
__global__ __launch_bounds__(256) void gemm3_kernel(
    const float* __restrict__ h, const float* __restrict__ W,
    const float* __restrict__ b, float* __restrict__ out) {
    const int c = threadIdx.x & 63;
    const int r = blockIdx.x * 4 + (threadIdx.x >> 6);
    if (r >= NNODES || c >= NCLASS) return;
    const float* hr = h + (size_t)r * NHID;
    float acc = b[c];
    #pragma unroll 4
    for (int k = 0; k < NHID; k += 4) {
        const float4 hv = *(const float4*)(hr + k);
        acc += hv.x * W[(k + 0) * NCLASS + c];
        acc += hv.y * W[(k + 1) * NCLASS + c];
        acc += hv.z * W[(k + 2) * NCLASS + c];
        acc += hv.w * W[(k + 3) * NCLASS + c];
    }
    out[(size_t)r * NCLASS + c] = acc;
}

// ===========================================================================
// CSR SpMM, 64 feats: wave per node, lane = feature. No atomics.
// out[n,f] = sum_{i in [rs[n],rs[n+1])} sup[edges[i].col, f] * edges[i].w
// ===========================================================================
__global__ __launch_bounds__(256) void spmm_csr64_kernel(
    const float* __restrict__ sup, const int2* __restrict__ edges,
    const int* __restrict__ row_start, float* __restrict__ out) {
    const int f = threadIdx.x & 63;
    const int n = blockIdx.x * 4 + (threadIdx.x >> 6);
    if (n >= NNODES) return;
    const int s = row_start[n];
    const int e = row_start[n + 1];
    float acc = 0.f;
    int i = s;
    for (; i + 1 < e; i += 2) {           // unroll-2 for memory-level parallelism
        const int2 e0 = edges[i];
        const int2 e1 = edges[i + 1];
        const float v0 = sup[(size_t)e0.x * NHID + f];
        const float v1 = sup[(size_t)e1.x * NHID + f];
        acc += v0 * __int_as_float(e0.y);
        acc += v1 * __int_as_float(e1.y);
    }
    if (i < e) {
        const int2 e0 = edges[i];
        acc += sup[(size_t)e0.x * NHID + f] * __int_as_float(e0.y);
    }
    out[(size_t)n * NHID + f] = acc;
}

// ===========================================================================
// CSR SpMM, 40 feats, fused log_softmax: wave per node.
// Lanes 40..63 idle in the edge loop, participate in shuffles.
// ===========================================================================
__global__ __launch_bounds__(256) void spmm_csr40_lsm_kernel(
    const float* __restrict__ sup, const int2* __restrict__ edges,
    const int* __restrict__ row_start, float* __restrict__ out) {
    const int f = threadIdx.x & 63;
    const int n = blockIdx.x * 4 + (threadIdx.x >> 6);
    if (n >= NNODES) return;
    const int s = row_start[n];
    const int e = row_start[n + 1];
    float acc = 0.f;
    if (f < NCLASS) {
        int i = s;
        for (; i + 1 < e; i += 2) {
            const int2 e0 = edges[i];
            const int2 e1 = edges[i + 1];
            const float v0 = sup[(size_t)e0.x * NCLASS + f];
            const float v1 = sup[(size_t)e1.x * NCLASS + f];
            acc += v0 * __int_as_float(e0.y);
            acc += v1 * __int_as_float(e1.y);
        }
        if (i < e) {
            const int2 e0 = edges[i];
            acc += sup[(size_t)e0.x * NCLASS + f] * __int_as_float(e0.y);
        }
    }
    // 64-lane max reduction
    float m = (f < NCLASS) ? acc : -1e30f;
    #pragma unroll
    for (int o = 32; o > 0; o >>= 1) m = fmaxf(m, __shfl_xor(m, o));
    // 64-lane sum of exp
    float ex = (f < NCLASS) ? __expf(acc - m) : 0.f;
    #pragma unroll
    for (int o = 32; o > 0; o >>= 1) ex += __shfl_xor(ex, o);
    const float ls = __logf(ex) + m;
    if (f < NCLASS) out[(size_t)n * NCLASS + f] = acc - ls;
}

// ===========================================================================
extern "C" void kernel_launch(void* const* d_in, const int* in_sizes, int n_in,
                              void* d_out, int out_size, void* d_ws, size_t ws_size,
                              hipStream_t stream) {
    const float* x  = (const float*)d_in[0];
    const float* ew = (const float*)d_in[1];
    const float* W1 = (const float*)d_in[2];
    const float* b1 = (const float*)d_in[3];
    const float* W2 = (const float*)d_in[4];
    const float* b2 = (const float*)d_in[5];
    const float* W3 = (const float*)d_in[6];
    const float* b3 = (const float*)d_in[7];
    const int* row  = (const int*)d_in[8];
    const int* col  = (const int*)d_in[9];
    float* out = (float*)d_out;

    // Workspace layout (~32.5 MB):
    const size_t n64 = (size_t)NNODES * NHID;
    float* A = (float*)d_ws;                  // support1 / support2 / support3
    float* B = A + n64;                       // h1 / h2
    int* deg       = (int*)(B + n64);         // NNODES
    int* cursor    = deg + NNODES;            // NNODES
    int* row_start = cursor + NNODES;         // NNODES + 2 (pad for int2 align)
    int* bsum      = row_start + NNODES + 2;  // 64
    int2* edges    = (int2*)(bsum + 64);      // NEDGES * 8 B = 6.4 MB

    const int tileBlocks = (NNODES + 63) / 64;
    const int nodeBlocks = (NNODES + 3) / 4;
    const int edgeBlocks = (NEDGES + 255) / 256;

    // ---- CSR build ----
    hipMemsetAsync(deg, 0, NNODES * sizeof(int), stream);
    hist_kernel<<<edgeBlocks, 256, 0, stream>>>(row, deg);
    scan1_kernel<<<SCAN_BLOCKS, 256, 0, stream>>>(deg, row_start, bsum);
    scan2_kernel<<<1, 64, 0, stream>>>(bsum);
    scan3_kernel<<<(NNODES + 255) / 256, 256, 0, stream>>>(row_start, bsum, cursor);
    scatter_kernel<<<edgeBlocks, 256, 0, stream>>>(row, col, ew, cursor, edges);

    // ---- Layer 1 ----
    tiled_gemm_kernel<NFEAT, false><<<tileBlocks, 256, 0, stream>>>(x, W1, b1, A);
    spmm_csr64_kernel<<<nodeBlocks, 256, 0, stream>>>(A, edges, row_start, B);

    // ---- Layer 2 (ReLU fused into staging read of h1) ----
    tiled_gemm_kernel<NHID, true><<<tileBlocks, 256, 0, stream>>>(B, W2, b2, A);
    spmm_csr64_kernel<<<nodeBlocks, 256, 0, stream>>>(A, edges, row_start, B);

    // ---- Layer 3 (support3 into A; SpMM + log_softmax fused -> d_out) ----
    gemm3_kernel<<<nodeBlocks, 256, 0, stream>>>(B, W3, b3, A);
    spmm_csr40_lsm_kernel<<<nodeBlocks, 256, 0, stream>>>(A, edges, row_start, out);
}